// Round 4
// baseline (490.447 us; speedup 1.0000x reference)
//
#include <hip/hip_runtime.h>
#include <hip/hip_cooperative_groups.h>
#include <hip/hip_bf16.h>
#include <math.h>

#define INV_T (1.0f / 0.07f)

typedef __bf16 bf16x8 __attribute__((ext_vector_type(8)));
typedef float f32x4 __attribute__((ext_vector_type(4)));

namespace cg = cooperative_groups;

__device__ __forceinline__ void gld16(const void* g, void* l) {
    __builtin_amdgcn_global_load_lds(
        (const __attribute__((address_space(1))) unsigned int*)g,
        (__attribute__((address_space(3))) unsigned int*)l,
        16, 0, 0);
}

__device__ __forceinline__ float agent_load(const float* p) {
    return __hip_atomic_load(p, __ATOMIC_RELAXED, __HIP_MEMORY_SCOPE_AGENT);
}

// ===================== single cooperative fused kernel =====================
// Phase 1: grid-strided row normalize -> F (bf16), P, S=0.
// Phase 2: work-stealing 128x256 sim tiles (body identical to the proven
//          round-0 kernel: XOR-swizzled LDS, gld16 staging, 16x16x32 MFMA,
//          strictly-upper exp + row/col atomic sums into S).
// Phase 3: block 0 computes the scalar loss.
__global__ __launch_bounds__(256, 3) void fused_kernel(
    const float4* __restrict__ f1, const float4* __restrict__ f2,
    ushort4* __restrict__ Fv, float* __restrict__ S, float* __restrict__ P,
    float* __restrict__ out, int* __restrict__ cnt,
    int B, int N, int D, int ntiles) {
    __shared__ __align__(16) __hip_bfloat16 As[128][64];  // 16 KB
    __shared__ __align__(16) __hip_bfloat16 Bs[256][64];  // 32 KB
    __shared__ float red[4][3];
    __shared__ float redf[4][2];
    __shared__ int kShared;

    const int tid  = threadIdx.x;
    const int wave = tid >> 6;
    const int lane = tid & 63;

    // ---------------- phase 1: normalize ----------------
    for (int i = blockIdx.x; i < B; i += gridDim.x) {
        float4 x = f1[i * 256 + tid];
        float4 y = f2[i * 256 + tid];

        float s1 = x.x * x.x + x.y * x.y + x.z * x.z + x.w * x.w;
        float s2 = y.x * y.x + y.y * y.y + y.z * y.z + y.w * y.w;
        float dd = x.x * y.x + x.y * y.y + x.z * y.z + x.w * y.w;

        for (int o = 32; o > 0; o >>= 1) {
            s1 += __shfl_down(s1, o);
            s2 += __shfl_down(s2, o);
            dd += __shfl_down(dd, o);
        }
        if (lane == 0) { red[wave][0] = s1; red[wave][1] = s2; red[wave][2] = dd; }
        __syncthreads();
        s1 = red[0][0] + red[1][0] + red[2][0] + red[3][0];
        s2 = red[0][1] + red[1][1] + red[2][1] + red[3][1];
        dd = red[0][2] + red[1][2] + red[2][2] + red[3][2];

        const float rn1 = 1.0f / fmaxf(sqrtf(s1), 1e-12f);
        const float rn2 = 1.0f / fmaxf(sqrtf(s2), 1e-12f);

        union { ushort4 u; __hip_bfloat16 h[4]; } p;
        p.h[0] = __float2bfloat16(x.x * rn1);
        p.h[1] = __float2bfloat16(x.y * rn1);
        p.h[2] = __float2bfloat16(x.z * rn1);
        p.h[3] = __float2bfloat16(x.w * rn1);
        Fv[(size_t)i * 256 + tid] = p.u;
        p.h[0] = __float2bfloat16(y.x * rn2);
        p.h[1] = __float2bfloat16(y.y * rn2);
        p.h[2] = __float2bfloat16(y.z * rn2);
        p.h[3] = __float2bfloat16(y.w * rn2);
        Fv[(size_t)(B + i) * 256 + tid] = p.u;

        if (tid == 0) {
            P[i] = dd * rn1 * rn2;
            S[i] = 0.0f;
            S[B + i] = 0.0f;
        }
        __syncthreads();   // red[] reuse guard for next grid-stride row
    }
    if (blockIdx.x == 0 && tid == 0) *cnt = 0;
    cg::this_grid().sync();   // F/P/S visible device-wide; cnt reset

    // ---------------- phase 2: sim tiles (work-stealing) ----------------
    const __hip_bfloat16* __restrict__ F = (const __hip_bfloat16*)Fv;

    const int quad = lane >> 4;
    const int l16  = lane & 15;
    const int srow   = lane >> 3;                 // 0..7
    const int ldsOff = (lane & 7) * 8;            // dest slot (elements)
    const int srcOff = ((lane & 7) ^ srow) * 8;   // swizzled global chunk
    const int waveRow = (wave >> 1) * 64;
    const int waveCol = (wave & 1) * 128;
    const int swz = l16 & 7;

    for (;;) {
        if (tid == 0) kShared = atomicAdd(cnt, 1);
        __syncthreads();
        const int k = kShared;
        if (k >= ntiles) break;

        // decode linear tile id -> (ti, tj): k = tj^2 + tj + ti
        int tj = (int)((sqrtf(4.0f * (float)k + 1.0f) - 1.0f) * 0.5f);
        while ((tj + 1) * (tj + 2) <= k) ++tj;
        while (tj * (tj + 1) > k) --tj;
        const int ti = k - tj * (tj + 1);  // in [0, 2*tj+2)
        const int bRow = ti * 128;
        const int bCol = tj * 256;

        f32x4 acc[4][8];
#pragma unroll
        for (int mi = 0; mi < 4; ++mi)
#pragma unroll
            for (int ni = 0; ni < 8; ++ni)
                acc[mi][ni] = (f32x4){0.0f, 0.0f, 0.0f, 0.0f};

        for (int kb = 0; kb < D; kb += 64) {
#pragma unroll
            for (int p = 0; p < 4; ++p) {
                const int rowT = (p * 4 + wave) * 8 + srow;   // 0..127
                gld16(&F[(size_t)(bRow + rowT) * D + kb + srcOff], &As[rowT][ldsOff]);
            }
#pragma unroll
            for (int p = 0; p < 8; ++p) {
                const int rowT = (p * 4 + wave) * 8 + srow;   // 0..255
                gld16(&F[(size_t)(bCol + rowT) * D + kb + srcOff], &Bs[rowT][ldsOff]);
            }
            __syncthreads();

#pragma unroll
            for (int ks = 0; ks < 2; ++ks) {
                const int slot = ((ks * 4 + quad) ^ swz) * 8;
                bf16x8 bf[8];
#pragma unroll
                for (int ni = 0; ni < 8; ++ni)
                    bf[ni] = *(const bf16x8*)&Bs[waveCol + ni * 16 + l16][slot];
#pragma unroll
                for (int mi = 0; mi < 4; ++mi) {
                    const bf16x8 af = *(const bf16x8*)&As[waveRow + mi * 16 + l16][slot];
#pragma unroll
                    for (int ni = 0; ni < 8; ++ni)
                        acc[mi][ni] = __builtin_amdgcn_mfma_f32_16x16x32_bf16(
                            af, bf[ni], acc[mi][ni], 0, 0, 0);
                }
            }
            __syncthreads();
        }

        // epilogue: e = (gRow<gCol) ? exp((c-1)/T) : 0; row+col sums
#pragma unroll
        for (int mi = 0; mi < 4; ++mi)
#pragma unroll
            for (int ni = 0; ni < 8; ++ni)
#pragma unroll
                for (int r = 0; r < 4; ++r) {
                    const int gRow = bRow + waveRow + mi * 16 + quad * 4 + r;
                    const int gCol = bCol + waveCol + ni * 16 + l16;
                    acc[mi][ni][r] = (gRow < gCol)
                        ? __expf((acc[mi][ni][r] - 1.0f) * INV_T) : 0.0f;
                }

#pragma unroll
        for (int mi = 0; mi < 4; ++mi)
#pragma unroll
            for (int r = 0; r < 4; ++r) {
                const int gRow = bRow + waveRow + mi * 16 + quad * 4 + r;
                float v = 0.0f;
#pragma unroll
                for (int ni = 0; ni < 8; ++ni) v += acc[mi][ni][r];
                v += __shfl_xor(v, 1);
                v += __shfl_xor(v, 2);
                v += __shfl_xor(v, 4);
                v += __shfl_xor(v, 8);
                if (l16 == 0) atomicAdd(&S[gRow], v);
            }

#pragma unroll
        for (int ni = 0; ni < 8; ++ni) {
            float cv = 0.0f;
#pragma unroll
            for (int mi = 0; mi < 4; ++mi)
#pragma unroll
                for (int r = 0; r < 4; ++r) cv += acc[mi][ni][r];
            cv += __shfl_xor(cv, 16);
            cv += __shfl_xor(cv, 32);
            if (quad == 0) atomicAdd(&S[bCol + waveCol + ni * 16 + l16], cv);
        }
    }

    cg::this_grid().sync();   // all S contributions done & visible

    // ---------------- phase 3: finalize (block 0 only) ----------------
    if (blockIdx.x != 0) return;

    float s0 = 0.0f, s1 = 0.0f, s2 = 0.0f, s3 = 0.0f;
    for (int i = tid; i < N; i += 1024) {   // N = 8192: 8 iters x 4 loads
        const float a = agent_load(&S[i]);
        const float b = agent_load(&S[i + 256]);
        const float c = agent_load(&S[i + 512]);
        const float d = agent_load(&S[i + 768]);
        s0 += __logf(a); s1 += __logf(b); s2 += __logf(c); s3 += __logf(d);
    }
    float s = (s0 + s1) + (s2 + s3);

    float pp = 0.0f;
    for (int i = tid; i < B; i += 1024) {   // B = 4096: 4 iters x 4 loads
        pp += agent_load(&P[i]) + agent_load(&P[i + 256]) +
              agent_load(&P[i + 512]) + agent_load(&P[i + 768]);
    }

    for (int o = 32; o > 0; o >>= 1) {
        s += __shfl_down(s, o);
        pp += __shfl_down(pp, o);
    }
    if (lane == 0) { redf[wave][0] = s; redf[wave][1] = pp; }
    __syncthreads();
    if (tid == 0) {
        const float sl = redf[0][0] + redf[1][0] + redf[2][0] + redf[3][0];
        const float ps = redf[0][1] + redf[1][1] + redf[2][1] + redf[3][1];
        out[0] = INV_T + sl / (float)N - ps * (2.0f * INV_T / (float)N);
    }
}

// ===================== fallback path (round-3, known-passing) ==============
__global__ __launch_bounds__(256) void norm_kernel(
    const float4* __restrict__ f1, const float4* __restrict__ f2,
    ushort4* __restrict__ F, float* __restrict__ S, float* __restrict__ P,
    int* __restrict__ cnt, int B) {
    const int i = blockIdx.x;
    const int t = threadIdx.x;

    float4 x = f1[i * 256 + t];
    float4 y = f2[i * 256 + t];

    float s1 = x.x * x.x + x.y * x.y + x.z * x.z + x.w * x.w;
    float s2 = y.x * y.x + y.y * y.y + y.z * y.z + y.w * y.w;
    float dd = x.x * y.x + x.y * y.y + x.z * y.z + x.w * y.w;

    for (int o = 32; o > 0; o >>= 1) {
        s1 += __shfl_down(s1, o);
        s2 += __shfl_down(s2, o);
        dd += __shfl_down(dd, o);
    }
    __shared__ float red[4][3];
    const int wv = t >> 6, ln = t & 63;
    if (ln == 0) { red[wv][0] = s1; red[wv][1] = s2; red[wv][2] = dd; }
    __syncthreads();
    s1 = red[0][0] + red[1][0] + red[2][0] + red[3][0];
    s2 = red[0][1] + red[1][1] + red[2][1] + red[3][1];
    dd = red[0][2] + red[1][2] + red[2][2] + red[3][2];

    const float rn1 = 1.0f / fmaxf(sqrtf(s1), 1e-12f);
    const float rn2 = 1.0f / fmaxf(sqrtf(s2), 1e-12f);

    union { ushort4 u; __hip_bfloat16 h[4]; } p;
    p.h[0] = __float2bfloat16(x.x * rn1);
    p.h[1] = __float2bfloat16(x.y * rn1);
    p.h[2] = __float2bfloat16(x.z * rn1);
    p.h[3] = __float2bfloat16(x.w * rn1);
    F[(size_t)i * 256 + t] = p.u;
    p.h[0] = __float2bfloat16(y.x * rn2);
    p.h[1] = __float2bfloat16(y.y * rn2);
    p.h[2] = __float2bfloat16(y.z * rn2);
    p.h[3] = __float2bfloat16(y.w * rn2);
    F[(size_t)(B + i) * 256 + t] = p.u;

    if (t == 0) {
        P[i] = dd * rn1 * rn2;
        S[i] = 0.0f;
        S[B + i] = 0.0f;
        if (i == 0) *cnt = 0;
    }
}

__global__ __launch_bounds__(256, 2) void sim_kernel(
    const __hip_bfloat16* __restrict__ F, float* __restrict__ S,
    const float* __restrict__ P, float* __restrict__ out,
    int* __restrict__ cnt, int N, int B, int D) {
    __shared__ __align__(16) __hip_bfloat16 As[128][64];
    __shared__ __align__(16) __hip_bfloat16 Bs[256][64];

    const int k = blockIdx.x;
    int tj = (int)((sqrtf(4.0f * (float)k + 1.0f) - 1.0f) * 0.5f);
    while ((tj + 1) * (tj + 2) <= k) ++tj;
    while (tj * (tj + 1) > k) --tj;
    const int ti = k - tj * (tj + 1);
    const int bRow = ti * 128;
    const int bCol = tj * 256;

    const int tid  = threadIdx.x;
    const int wave = tid >> 6;
    const int lane = tid & 63;
    const int quad = lane >> 4;
    const int l16  = lane & 15;

    const int srow   = lane >> 3;
    const int ldsOff = (lane & 7) * 8;
    const int srcOff = ((lane & 7) ^ srow) * 8;

    const int waveRow = (wave >> 1) * 64;
    const int waveCol = (wave & 1) * 128;
    const int swz = l16 & 7;

    f32x4 acc[4][8];
#pragma unroll
    for (int mi = 0; mi < 4; ++mi)
#pragma unroll
        for (int ni = 0; ni < 8; ++ni)
            acc[mi][ni] = (f32x4){0.0f, 0.0f, 0.0f, 0.0f};

    for (int kb = 0; kb < D; kb += 64) {
#pragma unroll
        for (int p = 0; p < 4; ++p) {
            const int rowT = (p * 4 + wave) * 8 + srow;
            gld16(&F[(size_t)(bRow + rowT) * D + kb + srcOff], &As[rowT][ldsOff]);
        }
#pragma unroll
        for (int p = 0; p < 8; ++p) {
            const int rowT = (p * 4 + wave) * 8 + srow;
            gld16(&F[(size_t)(bCol + rowT) * D + kb + srcOff], &Bs[rowT][ldsOff]);
        }
        __syncthreads();

#pragma unroll
        for (int ks = 0; ks < 2; ++ks) {
            const int slot = ((ks * 4 + quad) ^ swz) * 8;
            bf16x8 bf[8];
#pragma unroll
            for (int ni = 0; ni < 8; ++ni)
                bf[ni] = *(const bf16x8*)&Bs[waveCol + ni * 16 + l16][slot];
#pragma unroll
            for (int mi = 0; mi < 4; ++mi) {
                const bf16x8 af = *(const bf16x8*)&As[waveRow + mi * 16 + l16][slot];
#pragma unroll
                for (int ni = 0; ni < 8; ++ni)
                    acc[mi][ni] = __builtin_amdgcn_mfma_f32_16x16x32_bf16(
                        af, bf[ni], acc[mi][ni], 0, 0, 0);
            }
        }
        __syncthreads();
    }

#pragma unroll
    for (int mi = 0; mi < 4; ++mi)
#pragma unroll
        for (int ni = 0; ni < 8; ++ni)
#pragma unroll
            for (int r = 0; r < 4; ++r) {
                const int gRow = bRow + waveRow + mi * 16 + quad * 4 + r;
                const int gCol = bCol + waveCol + ni * 16 + l16;
                acc[mi][ni][r] = (gRow < gCol)
                    ? __expf((acc[mi][ni][r] - 1.0f) * INV_T) : 0.0f;
            }

#pragma unroll
    for (int mi = 0; mi < 4; ++mi)
#pragma unroll
        for (int r = 0; r < 4; ++r) {
            const int gRow = bRow + waveRow + mi * 16 + quad * 4 + r;
            float v = 0.0f;
#pragma unroll
            for (int ni = 0; ni < 8; ++ni) v += acc[mi][ni][r];
            v += __shfl_xor(v, 1);
            v += __shfl_xor(v, 2);
            v += __shfl_xor(v, 4);
            v += __shfl_xor(v, 8);
            if (l16 == 0) atomicAdd(&S[gRow], v);
        }

#pragma unroll
    for (int ni = 0; ni < 8; ++ni) {
        float cv = 0.0f;
#pragma unroll
        for (int mi = 0; mi < 4; ++mi)
#pragma unroll
            for (int r = 0; r < 4; ++r) cv += acc[mi][ni][r];
        cv += __shfl_xor(cv, 16);
        cv += __shfl_xor(cv, 32);
        if (quad == 0) atomicAdd(&S[bCol + waveCol + ni * 16 + l16], cv);
    }

    asm volatile("s_waitcnt vmcnt(0) lgkmcnt(0)" ::: "memory");
    __shared__ int lastFlag;
    if (tid == 0) lastFlag = (atomicAdd(cnt, 1) == (int)gridDim.x - 1);
    __syncthreads();
    if (!lastFlag) return;

    float s = 0.0f;
    for (int i = tid; i < N; i += 256) s += __logf(atomicAdd(&S[i], 0.0f));
    float pp = 0.0f;
    for (int i = tid; i < B; i += 256) pp += P[i];
    for (int o = 32; o > 0; o >>= 1) {
        s += __shfl_down(s, o);
        pp += __shfl_down(pp, o);
    }
    __shared__ float redf[4][2];
    if (lane == 0) { redf[wave][0] = s; redf[wave][1] = pp; }
    __syncthreads();
    if (tid == 0) {
        const float sl = redf[0][0] + redf[1][0] + redf[2][0] + redf[3][0];
        const float ps = redf[0][1] + redf[1][1] + redf[2][1] + redf[3][1];
        out[0] = INV_T + sl / (float)N - ps * (2.0f * INV_T / (float)N);
    }
}

// ===================== launch =====================
extern "C" void kernel_launch(void* const* d_in, const int* in_sizes, int n_in,
                              void* d_out, int out_size, void* d_ws, size_t ws_size,
                              hipStream_t stream) {
    const int D = 1024;
    const int B = in_sizes[0] / D;   // 4096
    const int N = 2 * B;             // 8192
    const int M2 = N / 256;          // 32 col-tiles
    const int ntiles = M2 * M2 + M2; // 1056

    const float* f1 = (const float*)d_in[0];
    const float* f2 = (const float*)d_in[1];

    __hip_bfloat16* F = (__hip_bfloat16*)d_ws;  // N*D bf16 = 16 MB
    float* S = (float*)((char*)d_ws + (size_t)N * D * sizeof(__hip_bfloat16));
    float* P = S + N;                // B floats
    int* cnt = (int*)(P + B);

    // one-time: co-residency capacity for the cooperative launch
    static int coopBlocks = -2;      // -2 = unqueried, -1 = unavailable
    if (coopBlocks == -2) {
        int maxb = 0;
        if (hipOccupancyMaxActiveBlocksPerMultiprocessor(
                &maxb, fused_kernel, 256, 0) == hipSuccess && maxb > 0) {
            int dev = 0;
            hipGetDevice(&dev);
            hipDeviceProp_t prop;
            int cus = 256;
            if (hipGetDeviceProperties(&prop, dev) == hipSuccess &&
                prop.multiProcessorCount > 0)
                cus = prop.multiProcessorCount;
            coopBlocks = maxb * cus;
        } else {
            coopBlocks = -1;
        }
    }

    bool done = false;
    if (coopBlocks > 0) {
        const float4* a1 = (const float4*)f1;
        const float4* a2 = (const float4*)f2;
        ushort4* Fv = (ushort4*)F;
        float* Sv = S;
        float* Pv = P;
        float* ov = (float*)d_out;
        int* cv = cnt;
        int Bi = B, Ni = N, Di = D, nt = ntiles;
        void* args[] = {&a1, &a2, &Fv, &Sv, &Pv, &ov, &cv, &Bi, &Ni, &Di, &nt};
        if (hipLaunchCooperativeKernel(fused_kernel, dim3(coopBlocks),
                                       dim3(256), args, 0, stream) == hipSuccess) {
            done = true;
        } else {
            coopBlocks = -1;   // don't retry on later calls
        }
    }

    if (!done) {
        norm_kernel<<<dim3(B), dim3(256), 0, stream>>>(
            (const float4*)f1, (const float4*)f2, (ushort4*)F, S, P, cnt, B);
        sim_kernel<<<dim3(ntiles), dim3(256), 0, stream>>>(
            F, S, P, (float*)d_out, cnt, N, B, D);
    }
}

// Round 5
// 171.226 us; speedup vs baseline: 2.8643x; 2.8643x over previous
//
#include <hip/hip_runtime.h>
#include <hip/hip_bf16.h>
#include <math.h>

#define INV_T (1.0f / 0.07f)

typedef __bf16 bf16x8 __attribute__((ext_vector_type(8)));
typedef float f32x4 __attribute__((ext_vector_type(4)));

__device__ __forceinline__ void gld16(const void* g, void* l) {
    __builtin_amdgcn_global_load_lds(
        (const __attribute__((address_space(1))) unsigned int*)g,
        (__attribute__((address_space(3))) unsigned int*)l,
        16, 0, 0);
}

// relaxed agent-scope atomic load: plain pipelined load that reads the
// coherent point (where the S atomicAdds live). NOT an RMW -> independent
// loads stay in flight together, no serialization.
__device__ __forceinline__ float agent_load(const float* p) {
    return __hip_atomic_load(p, __ATOMIC_RELAXED, __HIP_MEMORY_SCOPE_AGENT);
}

// ---------------- normalize + bf16 pack + positive dot + S-zero ------------
// one block per pair-row i; also zeroes S[i], S[B+i]; P[i] = cos(f1_i,f2_i)
__global__ __launch_bounds__(256) void norm_kernel(
    const float4* __restrict__ f1, const float4* __restrict__ f2,
    ushort4* __restrict__ F, float* __restrict__ S, float* __restrict__ P,
    int* __restrict__ cnt, int B) {
    const int i = blockIdx.x;
    const int t = threadIdx.x;

    float4 x = f1[i * 256 + t];
    float4 y = f2[i * 256 + t];

    float s1 = x.x * x.x + x.y * x.y + x.z * x.z + x.w * x.w;
    float s2 = y.x * y.x + y.y * y.y + y.z * y.z + y.w * y.w;
    float dd = x.x * y.x + x.y * y.y + x.z * y.z + x.w * y.w;

    for (int o = 32; o > 0; o >>= 1) {
        s1 += __shfl_down(s1, o);
        s2 += __shfl_down(s2, o);
        dd += __shfl_down(dd, o);
    }
    __shared__ float red[4][3];
    const int wv = t >> 6, ln = t & 63;
    if (ln == 0) { red[wv][0] = s1; red[wv][1] = s2; red[wv][2] = dd; }
    __syncthreads();
    s1 = red[0][0] + red[1][0] + red[2][0] + red[3][0];
    s2 = red[0][1] + red[1][1] + red[2][1] + red[3][1];
    dd = red[0][2] + red[1][2] + red[2][2] + red[3][2];

    const float rn1 = 1.0f / fmaxf(sqrtf(s1), 1e-12f);
    const float rn2 = 1.0f / fmaxf(sqrtf(s2), 1e-12f);

    union { ushort4 u; __hip_bfloat16 h[4]; } p;
    p.h[0] = __float2bfloat16(x.x * rn1);
    p.h[1] = __float2bfloat16(x.y * rn1);
    p.h[2] = __float2bfloat16(x.z * rn1);
    p.h[3] = __float2bfloat16(x.w * rn1);
    F[(size_t)i * 256 + t] = p.u;
    p.h[0] = __float2bfloat16(y.x * rn2);
    p.h[1] = __float2bfloat16(y.y * rn2);
    p.h[2] = __float2bfloat16(y.z * rn2);
    p.h[3] = __float2bfloat16(y.w * rn2);
    F[(size_t)(B + i) * 256 + t] = p.u;

    if (t == 0) {
        P[i] = dd * rn1 * rn2;
        S[i] = 0.0f;
        S[B + i] = 0.0f;
        if (i == 0) *cnt = 0;
    }
}

// ---------------- fused sim-GEMM + exp + row/col-sum (upper triangle) ------
// 128x256 block tile (rows ti*128, cols tj*256), tiles with ti <= 2*tj+1.
// Rule: count ONLY strictly-upper elements (gRow < gCol); credit exp to both
// S[gRow] and S[gCol]. Each unordered pair is computed exactly once; diagonal
// excluded automatically. 4 waves in 2x2, each wave 64x128 (4x8 of 16x16x32).
// XOR-swizzled LDS: chunk slot s at row r holds global chunk s^(r&7).
// Last-finishing block runs the finalize with PIPELINED relaxed agent loads
// (R3's atomicAdd-RMW tail cost ~37us serialized; this is ~3us).
// NOTE: __launch_bounds__(256,2) — do NOT raise min-waves (R4: 3 waves/EU
// capped VGPRs at 84 and spilled the 128-VGPR accumulator to scratch).
__global__ __launch_bounds__(256, 2) void sim_kernel(
    const __hip_bfloat16* __restrict__ F, float* __restrict__ S,
    const float* __restrict__ P, float* __restrict__ out,
    int* __restrict__ cnt, int N, int B, int D) {
    __shared__ __align__(16) __hip_bfloat16 As[128][64];  // 16 KB
    __shared__ __align__(16) __hip_bfloat16 Bs[256][64];  // 32 KB

    // ---- decode linear block id -> (ti, tj): k = tj^2 + tj + ti ----
    const int k = blockIdx.x;
    int tj = (int)((sqrtf(4.0f * (float)k + 1.0f) - 1.0f) * 0.5f);
    while ((tj + 1) * (tj + 2) <= k) ++tj;
    while (tj * (tj + 1) > k) --tj;
    const int ti = k - tj * (tj + 1);  // in [0, 2*tj+2)
    const int bRow = ti * 128;
    const int bCol = tj * 256;

    const int tid  = threadIdx.x;
    const int wave = tid >> 6;
    const int lane = tid & 63;
    const int quad = lane >> 4;
    const int l16  = lane & 15;

    const int srow   = lane >> 3;                 // 0..7
    const int ldsOff = (lane & 7) * 8;            // dest slot (elements)
    const int srcOff = ((lane & 7) ^ srow) * 8;   // swizzled global chunk

    const int waveRow = (wave >> 1) * 64;
    const int waveCol = (wave & 1) * 128;
    const int swz = l16 & 7;

    f32x4 acc[4][8];
#pragma unroll
    for (int mi = 0; mi < 4; ++mi)
#pragma unroll
        for (int ni = 0; ni < 8; ++ni)
            acc[mi][ni] = (f32x4){0.0f, 0.0f, 0.0f, 0.0f};

    for (int kb = 0; kb < D; kb += 64) {
#pragma unroll
        for (int p = 0; p < 4; ++p) {
            const int rowT = (p * 4 + wave) * 8 + srow;   // 0..127
            gld16(&F[(size_t)(bRow + rowT) * D + kb + srcOff], &As[rowT][ldsOff]);
        }
#pragma unroll
        for (int p = 0; p < 8; ++p) {
            const int rowT = (p * 4 + wave) * 8 + srow;   // 0..255
            gld16(&F[(size_t)(bCol + rowT) * D + kb + srcOff], &Bs[rowT][ldsOff]);
        }
        __syncthreads();

#pragma unroll
        for (int ks = 0; ks < 2; ++ks) {
            const int slot = ((ks * 4 + quad) ^ swz) * 8;
            bf16x8 bf[8];
#pragma unroll
            for (int ni = 0; ni < 8; ++ni)
                bf[ni] = *(const bf16x8*)&Bs[waveCol + ni * 16 + l16][slot];
#pragma unroll
            for (int mi = 0; mi < 4; ++mi) {
                const bf16x8 af = *(const bf16x8*)&As[waveRow + mi * 16 + l16][slot];
#pragma unroll
                for (int ni = 0; ni < 8; ++ni)
                    acc[mi][ni] = __builtin_amdgcn_mfma_f32_16x16x32_bf16(
                        af, bf[ni], acc[mi][ni], 0, 0, 0);
            }
        }
        __syncthreads();
    }

    // ---- epilogue: e = (gRow<gCol) ? exp((c-1)/T) : 0; row+col sums ----
#pragma unroll
    for (int mi = 0; mi < 4; ++mi)
#pragma unroll
        for (int ni = 0; ni < 8; ++ni)
#pragma unroll
            for (int r = 0; r < 4; ++r) {
                const int gRow = bRow + waveRow + mi * 16 + quad * 4 + r;
                const int gCol = bCol + waveCol + ni * 16 + l16;
                acc[mi][ni][r] = (gRow < gCol)
                    ? __expf((acc[mi][ni][r] - 1.0f) * INV_T) : 0.0f;
            }

    // row sums
#pragma unroll
    for (int mi = 0; mi < 4; ++mi)
#pragma unroll
        for (int r = 0; r < 4; ++r) {
            const int gRow = bRow + waveRow + mi * 16 + quad * 4 + r;
            float v = 0.0f;
#pragma unroll
            for (int ni = 0; ni < 8; ++ni) v += acc[mi][ni][r];
            v += __shfl_xor(v, 1);
            v += __shfl_xor(v, 2);
            v += __shfl_xor(v, 4);
            v += __shfl_xor(v, 8);
            if (l16 == 0) atomicAdd(&S[gRow], v);
        }

    // col sums (transpose contribution)
#pragma unroll
    for (int ni = 0; ni < 8; ++ni) {
        float cv = 0.0f;
#pragma unroll
        for (int mi = 0; mi < 4; ++mi)
#pragma unroll
            for (int r = 0; r < 4; ++r) cv += acc[mi][ni][r];
        cv += __shfl_xor(cv, 16);
        cv += __shfl_xor(cv, 32);
        if (quad == 0) atomicAdd(&S[bCol + waveCol + ni * 16 + l16], cv);
    }

    // ---- last-block-done finalize ----
    // Drain OUR outstanding S-atomics before signalling. All S/cnt traffic
    // is device-scope atomics at the coherent point: cnt==grid-1 implies
    // every block's S-adds completed there. No agent fence (R2 lesson: the
    // fence's L2 invalidate poisons co-resident GEMM blocks).
    asm volatile("s_waitcnt vmcnt(0) lgkmcnt(0)" ::: "memory");
    __shared__ int lastFlag;
    if (tid == 0) lastFlag = (atomicAdd(cnt, 1) == (int)gridDim.x - 1);
    __syncthreads();
    if (!lastFlag) return;

    // Pipelined coherent reads: 4 independent loads per batch stay in
    // flight together (vs R3's strictly-serialized atomicAdd RMWs).
    float s0 = 0.0f, s1 = 0.0f, s2 = 0.0f, s3 = 0.0f;
    for (int i = tid; i < N; i += 1024) {      // N=8192: 8 iters x 4 loads
        const float a = agent_load(&S[i]);
        const float b = agent_load(&S[i + 256]);
        const float c = agent_load(&S[i + 512]);
        const float d = agent_load(&S[i + 768]);
        s0 += __logf(a); s1 += __logf(b); s2 += __logf(c); s3 += __logf(d);
    }
    float s = (s0 + s1) + (s2 + s3);

    // P written by norm_kernel (prior dispatch) -> plain loads are coherent.
    float pp = 0.0f;
    for (int i = tid; i < B; i += 1024)        // B=4096: 4 iters x 4 loads
        pp += P[i] + P[i + 256] + P[i + 512] + P[i + 768];

    for (int o = 32; o > 0; o >>= 1) {
        s += __shfl_down(s, o);
        pp += __shfl_down(pp, o);
    }
    __shared__ float redf[4][2];
    if (lane == 0) { redf[wave][0] = s; redf[wave][1] = pp; }
    __syncthreads();
    if (tid == 0) {
        const float sl = redf[0][0] + redf[1][0] + redf[2][0] + redf[3][0];
        const float ps = redf[0][1] + redf[1][1] + redf[2][1] + redf[3][1];
        out[0] = INV_T + sl / (float)N - ps * (2.0f * INV_T / (float)N);
    }
}

extern "C" void kernel_launch(void* const* d_in, const int* in_sizes, int n_in,
                              void* d_out, int out_size, void* d_ws, size_t ws_size,
                              hipStream_t stream) {
    const int D = 1024;
    const int B = in_sizes[0] / D;   // 4096
    const int N = 2 * B;             // 8192
    const int M2 = N / 256;          // 32 col-tiles
    const int ntiles = M2 * M2 + M2; // sum over tj of (2*tj+2) = 1056

    const float* f1 = (const float*)d_in[0];
    const float* f2 = (const float*)d_in[1];

    __hip_bfloat16* F = (__hip_bfloat16*)d_ws;  // N*D bf16 = 16 MB
    float* S = (float*)((char*)d_ws + (size_t)N * D * sizeof(__hip_bfloat16));
    float* P = S + N;                // B floats
    int* cnt = (int*)(P + B);

    norm_kernel<<<dim3(B), dim3(256), 0, stream>>>(
        (const float4*)f1, (const float4*)f2, (ushort4*)F, S, P, cnt, B);
    sim_kernel<<<dim3(ntiles), dim3(256), 0, stream>>>(
        F, S, P, (float*)d_out, cnt, N, B, D);
}